// Round 20
// baseline (131.061 us; speedup 1.0000x reference)
//
#include <hip/hip_runtime.h>
#include <math.h>

// Problem constants (from reference)
#define BB     8192      // batch
#define DD     512       // embed dim
#define NEXP   16        // expansions per sample
#define TOPK   2048      // round(B * 0.25)
#define AUGX_ROWS (BB + TOPK * NEXP)              // 40960
#define AUGT_OFF  ((size_t)AUGX_ROWS * DD)        // 20971520
#define ISEXP_OFF (AUGT_OFF + AUGX_ROWS)          // 21012480

#define JCHUNK 256       // j-scores per rank block
#define COPY_BLOCKS 2048 // 64-thr copy blocks tail-filling expand's grid
#define BMP 520          // bf16 row pitch: 1040 B = 16B-aligned, bank step 4

typedef __attribute__((ext_vector_type(8)))  short bf16x8;
typedef __attribute__((ext_vector_type(16))) float f32x16;

__device__ inline ushort f2bf(float f) {   // RNE f32 -> bf16 bits
    uint u = __builtin_bit_cast(uint, f);
    return (ushort)((u + 0x7FFFu + ((u >> 16) & 1u)) >> 16);
}
__device__ inline float bf2f(ushort b) {
    uint u = ((uint)b) << 16;
    return __builtin_bit_cast(float, u);
}

// ---------------------------------------------------------------------------
// Kernel 1: per-sample score in f64 (matches harness ordering at ties).
// One WAVE per sample, 4 samples per 256-thr block. Emits header
// {xn, pn, zw, r1n} and zeroes ranks[] (replaces separate memset dispatch).
__global__ __launch_bounds__(256) void score_kernel(
    const float* __restrict__ x, const int* __restrict__ y,
    const float* __restrict__ prox, double* __restrict__ scores,
    float4* __restrict__ hdr, int* __restrict__ ranks)
{
    int wave = threadIdx.x >> 6, lane = threadIdx.x & 63;
    int i = blockIdx.x * 4 + wave;
    const float* xr = x + (size_t)i * DD;
    const float* pr = prox + (size_t)y[i] * DD;
    double sx = 0.0, sp = 0.0, dp = 0.0;
    #pragma unroll
    for (int e = 0; e < DD; e += 64) {
        float xv = xr[e + lane];
        float pv = pr[e + lane];
        sx += (double)xv * (double)xv;
        sp += (double)pv * (double)pv;
        dp += (double)xv * (double)pv;
    }
    #pragma unroll
    for (int off = 32; off > 0; off >>= 1) {
        sx += __shfl_down(sx, off);
        sp += __shfl_down(sp, off);
        dp += __shfl_down(dp, off);
    }
    if (lane == 0) {
        double xn = sqrt(sx + 1e-12), pn = sqrt(sp + 1e-12);
        double zw = dp / (xn * pn);
        scores[i] = zw;
        double r1sq = 1.0 - zw * zw;
        if (r1sq < 1e-12) r1sq = 1e-12;
        float4 h = { (float)xn, (float)pn, (float)zw, (float)sqrt(r1sq) };
        hdr[i] = h;
        ranks[i] = 0;
    }
}

// ---------------------------------------------------------------------------
// Kernel 2: partial rank accumulation; tie-break = jax.lax.top_k stability.
// Integer atomics only (exact, order-independent).
__global__ __launch_bounds__(256) void rank_kernel(
    const double* __restrict__ scores, int* __restrict__ ranks)
{
    __shared__ double ch[JCHUNK];
    int i = blockIdx.x * 256 + threadIdx.x;
    int jbase = blockIdx.y * JCHUNK;
    double si = scores[i];
    if (threadIdx.x < JCHUNK) ch[threadIdx.x] = scores[jbase + threadIdx.x];
    __syncthreads();
    int rank = 0;
    #pragma unroll 8
    for (int j = 0; j < JCHUNK; ++j) {
        double sj = ch[j];
        int jj = jbase + j;
        rank += (sj > si || (sj == si && jj < i)) ? 1 : 0;
    }
    atomicAdd(&ranks[i], rank);
}

// ---------------------------------------------------------------------------
// Kernel 3: ordered compaction (ascending sel[]), write is_expan floats.
__global__ __launch_bounds__(256) void compact_kernel(
    const int* __restrict__ ranks, int* __restrict__ sel, float* __restrict__ out)
{
    __shared__ int wsum[4];
    int t = threadIdx.x;
    int base = t * 32;
    int fl[32];
    int cnt = 0;
    #pragma unroll
    for (int q = 0; q < 8; ++q) {
        int4 rv = *(const int4*)&ranks[base + q * 4];
        fl[q * 4 + 0] = (rv.x < TOPK) ? 1 : 0;
        fl[q * 4 + 1] = (rv.y < TOPK) ? 1 : 0;
        fl[q * 4 + 2] = (rv.z < TOPK) ? 1 : 0;
        fl[q * 4 + 3] = (rv.w < TOPK) ? 1 : 0;
        cnt += fl[q*4] + fl[q*4+1] + fl[q*4+2] + fl[q*4+3];
    }
    int lane = t & 63, wave = t >> 6;
    int inc = cnt;
    #pragma unroll
    for (int off = 1; off < 64; off <<= 1) {
        int n = __shfl_up(inc, off);
        if (lane >= off) inc += n;
    }
    if (lane == 63) wsum[wave] = inc;
    __syncthreads();
    int wbase = 0;
    for (int w = 0; w < wave; ++w) wbase += wsum[w];
    int pos = wbase + inc - cnt;
    #pragma unroll
    for (int q = 0; q < 8; ++q) {
        float4 ev = { fl[q*4] ? 1.0f : 0.0f, fl[q*4+1] ? 1.0f : 0.0f,
                      fl[q*4+2] ? 1.0f : 0.0f, fl[q*4+3] ? 1.0f : 0.0f };
        *(float4*)&out[ISEXP_OFF + base + q * 4] = ev;
        #pragma unroll
        for (int i = 0; i < 4; ++i)
            if (fl[q * 4 + i]) sel[pos++] = base + q * 4 + i;
    }
}

// ---------------------------------------------------------------------------
// Kernel 5: ONE WAVE PER SAMPLE, ZERO BARRIERS (blocks 0..TOPK-1); raw-x copy
// on blocks >= TOPK. All cross-phase dependencies are same-wave LDS ordering
// (in-order, lgkmcnt-enforced). Phases: stage bf16 basis -> 32-MFMA Gram
// (K=512, 2 interleaved accs) -> register Cholesky (R9-R11-proven) ->
// back-solve C = bw_ext @ L^-1 -> streamed output GEMM. Waves never wait on
// each other; BW and compute phases of ~7 resident waves/CU self-interleave.
// LDS 21368 B -> 7 blocks/CU.
__global__ __launch_bounds__(64, 2) void expand_kernel(
    const float* __restrict__ x, const int* __restrict__ y,
    const float* __restrict__ prox, const float* __restrict__ bwg,
    const float* __restrict__ rands, const int* __restrict__ sel,
    const float4* __restrict__ hdr, float* __restrict__ out)
{
    const int lane = threadIdx.x;   // 0..63, block == wave

    // ---- fused copy blocks: aug_x[0:B] = x, aug_t[0:B] = y
    if (blockIdx.x >= TOPK) {
        int tid = (blockIdx.x - TOPK) * 64 + lane;
        const float4* src = (const float4*)x;
        float4* dst = (float4*)out;
        const int nvec = BB * DD / 4;
        for (int idx = tid; idx < nvec; idx += COPY_BLOCKS * 64) dst[idx] = src[idx];
        for (int i = tid; i < BB; i += COPY_BLOCKS * 64) out[AUGT_OFF + i] = (float)y[i];
        return;
    }

    __shared__ ushort Bm[18][BMP];   // bf16 basis rows            18720 B
    __shared__ float LsGs[18][19];   // Gram, then L (in place)     1368 B
    __shared__ float CsP[16][20];    // C rows, padded to float4    1280 B

    const int j = blockIdx.x;
    const int s = sel[j];
    const int cls = y[s];

    // ---- stage 16 rand rows (two coalesced float4 halves per row)
    const float* rbase = rands + (size_t)j * NEXP * DD;
    #pragma unroll
    for (int row = 0; row < 16; ++row) {
        float4 a = *(const float4*)(rbase + row * DD + lane * 4);
        float4 b = *(const float4*)(rbase + row * DD + 256 + lane * 4);
        ushort4 la = { f2bf(a.x), f2bf(a.y), f2bf(a.z), f2bf(a.w) };
        ushort4 lb = { f2bf(b.x), f2bf(b.y), f2bf(b.z), f2bf(b.w) };
        *(ushort4*)&Bm[2 + row][lane * 4] = la;
        *(ushort4*)&Bm[2 + row][256 + lane * 4] = lb;
    }

    // ---- w, u1 rows; lane owns dims {cc*128 + lane*2, +1} for cc=0..3
    float4 h = hdr[s];
    const float zw = h.z, r1n = h.w;
    const float ixn = 1.0f / h.x, ipn = 1.0f / h.y, ir1 = 1.0f / r1n;

    float2 wv[4];
    #pragma unroll
    for (int cc = 0; cc < 4; ++cc) {
        int d = cc * 128 + lane * 2;
        float2 xv = *(const float2*)(x + (size_t)s * DD + d);
        float2 pv = *(const float2*)(prox + (size_t)cls * DD + d);
        float2 w = { pv.x * ipn, pv.y * ipn };
        float2 z = { xv.x * ixn, xv.y * ixn };
        float2 u = { (z.x - zw * w.x) * ir1, (z.y - zw * w.y) * ir1 };
        wv[cc] = w;
        ushort2 wb = { f2bf(w.x), f2bf(w.y) };
        ushort2 ub = { f2bf(u.x), f2bf(u.y) };
        *(ushort2*)&Bm[0][d] = wb;
        *(ushort2*)&Bm[1][d] = ub;
    }

    // expansion labels (independent)
    if (lane < NEXP) out[AUGT_OFF + BB + (size_t)j * NEXP + lane] = (float)cls;

    // ---- Gram over full K=512: 32 chained MFMAs, 2 interleaved accumulators.
    // Same-wave LDS ordering: all Bm writes above precede these reads.
    {
        int row = lane & 31; if (row > 17) row = 17;
        int koff = (lane >> 5) * 8;
        f32x16 accA = {0,0,0,0,0,0,0,0,0,0,0,0,0,0,0,0};
        f32x16 accB = {0,0,0,0,0,0,0,0,0,0,0,0,0,0,0,0};
        #pragma unroll
        for (int stp = 0; stp < 32; stp += 2) {
            bf16x8 a0 = *(const bf16x8*)&Bm[row][stp * 16 + koff];
            bf16x8 a1 = *(const bf16x8*)&Bm[row][(stp + 1) * 16 + koff];
            accA = __builtin_amdgcn_mfma_f32_32x32x16_bf16(a0, a0, accA, 0, 0, 0);
            accB = __builtin_amdgcn_mfma_f32_32x32x16_bf16(a1, a1, accB, 0, 0, 0);
        }
        // D layout: col = lane&31, row = (reg&3) + 8*(reg>>2) + 4*(lane>>5)
        int col = lane & 31;
        if (col < 18) {
            #pragma unroll
            for (int rg = 0; rg < 16; ++rg) {
                int rr = (rg & 3) + 8 * (rg >> 2) + 4 * (lane >> 5);
                if (rr < 18) LsGs[rr][col] = accA[rg] + accB[rg];
            }
        }
    }

    // ---- register right-looking Cholesky (lane = row; lanes>=18 dup row 17)
    const int jl = (lane < 18) ? lane : 17;
    float Greg[18];
    #pragma unroll
    for (int c = 0; c < 18; ++c) Greg[c] = LsGs[jl][c];

    float Lrow[18], idr[18];
    #pragma unroll
    for (int col = 0; col < 18; ++col) {
        float pivot = __shfl(Greg[col], col);   // fully-updated diagonal
        float rsq = rsqrtf(pivot);
        idr[col] = rsq;
        float lv = (jl >= col) ? Greg[col] * rsq : 0.0f;
        Lrow[col] = lv;
        #pragma unroll
        for (int c = col + 1; c < 18; ++c) {    // Schur update
            float lc = __shfl(lv, c);           // L[c][col]
            Greg[c] -= lv * lc;
        }
    }
    #pragma unroll
    for (int c = 0; c < 18; ++c) LsGs[jl][c] = Lrow[c];

    // ---- back-substitution, lanes 0..15: solve L^T c = bw_ext_r (r = lane)
    if (lane < 16) {
        float b[18];
        b[0] = 0.0f;
        #pragma unroll
        for (int m = 1; m < 18; ++m) b[m] = bwg[17 + lane * 17 + (m - 1)];
        #pragma unroll
        for (int k = 17; k >= 0; --k) {
            float xk = b[k] * idr[k];
            CsP[lane][k] = xk;
            #pragma unroll
            for (int m = 0; m < k; ++m)
                b[m] -= LsGs[k][m] * xk;        // broadcast reads of row k
        }
        CsP[lane][18] = 0.0f; CsP[lane][19] = 0.0f;  // pad (vector reads)
    }

    // ---- outputs: out_r = M + r1n * sum_j C[r][j] * b_j; 4 chunks of 2 dims
    float* orow = out + ((size_t)BB + (size_t)j * NEXP) * DD;
    #pragma unroll
    for (int cc = 0; cc < 4; ++cc) {
        int d = cc * 128 + lane * 2;
        float bx[18], by[18];
        #pragma unroll
        for (int jj = 0; jj < 18; ++jj) {
            uint v = *(const uint*)&Bm[jj][d];
            bx[jj] = bf2f((ushort)(v & 0xffffu));
            by[jj] = bf2f((ushort)(v >> 16));
        }
        float Mx = zw * wv[cc].x, My = zw * wv[cc].y;
        #pragma unroll
        for (int r = 0; r < 16; ++r) {
            float4 c0 = *(const float4*)&CsP[r][0];
            float4 c1 = *(const float4*)&CsP[r][4];
            float4 c2 = *(const float4*)&CsP[r][8];
            float4 c3 = *(const float4*)&CsP[r][12];
            float2 c4 = *(const float2*)&CsP[r][16];
            float a0 = c0.x*bx[0] + c0.y*bx[1] + c0.z*bx[2] + c0.w*bx[3]
                     + c1.x*bx[4] + c1.y*bx[5] + c1.z*bx[6] + c1.w*bx[7]
                     + c2.x*bx[8] + c2.y*bx[9] + c2.z*bx[10] + c2.w*bx[11]
                     + c3.x*bx[12] + c3.y*bx[13] + c3.z*bx[14] + c3.w*bx[15]
                     + c4.x*bx[16] + c4.y*bx[17];
            float a1 = c0.x*by[0] + c0.y*by[1] + c0.z*by[2] + c0.w*by[3]
                     + c1.x*by[4] + c1.y*by[5] + c1.z*by[6] + c1.w*by[7]
                     + c2.x*by[8] + c2.y*by[9] + c2.z*by[10] + c2.w*by[11]
                     + c3.x*by[12] + c3.y*by[13] + c3.z*by[14] + c3.w*by[15]
                     + c4.x*by[16] + c4.y*by[17];
            float2 ov = { Mx + r1n * a0, My + r1n * a1 };
            *(float2*)(orow + (size_t)r * DD + d) = ov;
        }
    }
}

// ---------------------------------------------------------------------------
extern "C" void kernel_launch(void* const* d_in, const int* in_sizes, int n_in,
                              void* d_out, int out_size, void* d_ws, size_t ws_size,
                              hipStream_t stream)
{
    const float* x     = (const float*)d_in[0];   // [8192,512]
    const int*   y     = (const int*)d_in[1];     // [8192]
    const float* prox  = (const float*)d_in[2];   // [11318,512]
    const float* bw    = (const float*)d_in[3];   // [17,17]
    const float* rands = (const float*)d_in[4];   // [2048,16,512]
    float* out = (float*)d_out;

    char* wsb = (char*)d_ws;
    double* scores = (double*)wsb;                            // 64 KB
    int* ranks = (int*)(wsb + 65536);                         // 32 KB
    int* sel   = (int*)(wsb + 65536 + 32768);                 // 8 KB
    float4* hdr = (float4*)(wsb + 114688);                    // 128 KB

    score_kernel<<<BB / 4, 256, 0, stream>>>(x, y, prox, scores, hdr, ranks);
    dim3 rgrid(BB / 256, BB / JCHUNK);
    rank_kernel<<<rgrid, 256, 0, stream>>>(scores, ranks);
    compact_kernel<<<1, 256, 0, stream>>>(ranks, sel, out);
    expand_kernel<<<TOPK + COPY_BLOCKS, 64, 0, stream>>>(x, y, prox, bw, rands,
                                                         sel, hdr, out);
}

// Round 21
// 61.584 us; speedup vs baseline: 2.1282x; 2.1282x over previous
//
#include <hip/hip_runtime.h>
#include <math.h>

// Problem constants (from reference)
#define BB     8192      // batch
#define DD     512       // embed dim
#define NEXP   16        // expansions per sample
#define TOPK   2048      // round(B * 0.25)
#define AUGX_ROWS (BB + TOPK * NEXP)              // 40960
#define AUGT_OFF  ((size_t)AUGX_ROWS * DD)        // 20971520
#define ISEXP_OFF (AUGT_OFF + AUGX_ROWS)          // 21012480

#define JCHUNK 256       // j-scores per rank block
#define COPY_BLOCKS 1024 // copy blocks interleaved into expand's grid
#define BMP 520          // bf16 row pitch: 1040 B = 16B-aligned, bank step 4

typedef __attribute__((ext_vector_type(8)))  short bf16x8;
typedef __attribute__((ext_vector_type(16))) float f32x16;

__device__ inline ushort f2bf(float f) {   // RNE f32 -> bf16 bits
    uint u = __builtin_bit_cast(uint, f);
    return (ushort)((u + 0x7FFFu + ((u >> 16) & 1u)) >> 16);
}
__device__ inline float bf2f(ushort b) {
    uint u = ((uint)b) << 16;
    return __builtin_bit_cast(float, u);
}

// ---------------------------------------------------------------------------
// Kernel 1: per-sample score in f64 (matches harness ordering at ties).
// One WAVE per sample, 4 samples per 256-thr block. Emits header
// {xn, pn, zw, r1n} and zeroes ranks[] (replaces separate memset dispatch).
__global__ __launch_bounds__(256) void score_kernel(
    const float* __restrict__ x, const int* __restrict__ y,
    const float* __restrict__ prox, double* __restrict__ scores,
    float4* __restrict__ hdr, int* __restrict__ ranks)
{
    int wave = threadIdx.x >> 6, lane = threadIdx.x & 63;
    int i = blockIdx.x * 4 + wave;
    const float* xr = x + (size_t)i * DD;
    const float* pr = prox + (size_t)y[i] * DD;
    double sx = 0.0, sp = 0.0, dp = 0.0;
    #pragma unroll
    for (int e = 0; e < DD; e += 64) {
        float xv = xr[e + lane];
        float pv = pr[e + lane];
        sx += (double)xv * (double)xv;
        sp += (double)pv * (double)pv;
        dp += (double)xv * (double)pv;
    }
    #pragma unroll
    for (int off = 32; off > 0; off >>= 1) {
        sx += __shfl_down(sx, off);
        sp += __shfl_down(sp, off);
        dp += __shfl_down(dp, off);
    }
    if (lane == 0) {
        double xn = sqrt(sx + 1e-12), pn = sqrt(sp + 1e-12);
        double zw = dp / (xn * pn);
        scores[i] = zw;
        double r1sq = 1.0 - zw * zw;
        if (r1sq < 1e-12) r1sq = 1e-12;
        float4 h = { (float)xn, (float)pn, (float)zw, (float)sqrt(r1sq) };
        hdr[i] = h;
        ranks[i] = 0;
    }
}

// ---------------------------------------------------------------------------
// Kernel 2: partial rank accumulation; tie-break = jax.lax.top_k stability.
// Integer atomics only (exact, order-independent).
__global__ __launch_bounds__(256) void rank_kernel(
    const double* __restrict__ scores, int* __restrict__ ranks)
{
    __shared__ double ch[JCHUNK];
    int i = blockIdx.x * 256 + threadIdx.x;
    int jbase = blockIdx.y * JCHUNK;
    double si = scores[i];
    if (threadIdx.x < JCHUNK) ch[threadIdx.x] = scores[jbase + threadIdx.x];
    __syncthreads();
    int rank = 0;
    #pragma unroll 8
    for (int j = 0; j < JCHUNK; ++j) {
        double sj = ch[j];
        int jj = jbase + j;
        rank += (sj > si || (sj == si && jj < i)) ? 1 : 0;
    }
    atomicAdd(&ranks[i], rank);
}

// ---------------------------------------------------------------------------
// Kernel 3: ordered compaction (ascending sel[]), write is_expan floats.
__global__ __launch_bounds__(256) void compact_kernel(
    const int* __restrict__ ranks, int* __restrict__ sel, float* __restrict__ out)
{
    __shared__ int wsum[4];
    int t = threadIdx.x;
    int base = t * 32;
    int fl[32];
    int cnt = 0;
    #pragma unroll
    for (int q = 0; q < 8; ++q) {
        int4 rv = *(const int4*)&ranks[base + q * 4];
        fl[q * 4 + 0] = (rv.x < TOPK) ? 1 : 0;
        fl[q * 4 + 1] = (rv.y < TOPK) ? 1 : 0;
        fl[q * 4 + 2] = (rv.z < TOPK) ? 1 : 0;
        fl[q * 4 + 3] = (rv.w < TOPK) ? 1 : 0;
        cnt += fl[q*4] + fl[q*4+1] + fl[q*4+2] + fl[q*4+3];
    }
    int lane = t & 63, wave = t >> 6;
    int inc = cnt;
    #pragma unroll
    for (int off = 1; off < 64; off <<= 1) {
        int n = __shfl_up(inc, off);
        if (lane >= off) inc += n;
    }
    if (lane == 63) wsum[wave] = inc;
    __syncthreads();
    int wbase = 0;
    for (int w = 0; w < wave; ++w) wbase += wsum[w];
    int pos = wbase + inc - cnt;
    #pragma unroll
    for (int q = 0; q < 8; ++q) {
        float4 ev = { fl[q*4] ? 1.0f : 0.0f, fl[q*4+1] ? 1.0f : 0.0f,
                      fl[q*4+2] ? 1.0f : 0.0f, fl[q*4+3] ? 1.0f : 0.0f };
        *(float4*)&out[ISEXP_OFF + base + q * 4] = ev;
        #pragma unroll
        for (int i = 0; i < 4; ++i)
            if (fl[q * 4 + i]) sel[pos++] = base + q * 4 + i;
    }
}

// ---------------------------------------------------------------------------
// Kernel 5: fused expansion + raw-x copy, INTERLEAVED (blockIdx%3==2 -> copy
// block; else expansion). Copy blocks are barrier-free pure streaming, so
// each CU's resident set mixes them with expansion blocks and their BW fills
// expansion's compute windows (anti-phase-lock). Expansion: stage bf16 basis
// -> 2-wave MFMA Gram -> wave0 register Cholesky -> back-solve C = bw_ext @
// L^-1 -> parallel output GEMM. Norms precomputed by score_kernel (3
// barriers). LDS 21456 B -> 7 blocks/CU.
__global__ __launch_bounds__(256, 7) void expand_kernel(
    const float* __restrict__ x, const int* __restrict__ y,
    const float* __restrict__ prox, const float* __restrict__ bwg,
    const float* __restrict__ rands, const int* __restrict__ sel,
    const float4* __restrict__ hdr, float* __restrict__ out)
{
    const int t = threadIdx.x;
    const int q = blockIdx.x / 3, r3 = blockIdx.x % 3;

    // ---- interleaved copy blocks: aug_x[0:B] = x, aug_t[0:B] = y
    if (r3 == 2) {
        int tid = q * 256 + t;
        const float4* src = (const float4*)x;
        float4* dst = (float4*)out;
        const int nvec = BB * DD / 4;
        for (int idx = tid; idx < nvec; idx += COPY_BLOCKS * 256) dst[idx] = src[idx];
        for (int i = tid; i < BB; i += COPY_BLOCKS * 256) out[AUGT_OFF + i] = (float)y[i];
        return;
    }

    __shared__ ushort Bm[18][BMP];   // bf16 basis rows            18720 B
    union SPool {
        float Gp[2][18][19];         // per-wave MFMA partials      2736 B
        struct { float Ls[18][19]; float Cs[16][18]; } s;  // 1368+1152 B
    };
    __shared__ SPool pool;

    const int j = 2 * q + r3;        // expansion sample 0..2047 (bijective)
    const int wave = t >> 6, lane = t & 63;
    const int s = sel[j];
    const int cls = y[s];

    // ---- stage 16 rand rows into LDS as bf16 (transient registers only)
    {
        const float* rbase = rands + (size_t)j * NEXP * DD;
        #pragma unroll
        for (int i = 0; i < 8; ++i) {
            int row = 2 * i + (t >> 7);
            int col = (t & 127) * 4;
            float4 vv = *(const float4*)(rbase + (size_t)row * DD + col);
            ushort4 bv = { f2bf(vv.x), f2bf(vv.y), f2bf(vv.z), f2bf(vv.w) };
            *(ushort4*)&Bm[2 + row][col] = bv;
        }
    }

    // ---- per-element w, u1 from precomputed norms (no reductions)
    float4 h = hdr[s];
    const float zw = h.z, r1n = h.w;
    const float ixn = 1.0f / h.x, ipn = 1.0f / h.y, ir1 = 1.0f / r1n;

    float2 xv = ((const float2*)(x + (size_t)s * DD))[t];
    float2 pv = ((const float2*)(prox + (size_t)cls * DD))[t];
    float2 w  = { pv.x * ipn, pv.y * ipn };
    float2 z  = { xv.x * ixn, xv.y * ixn };
    float2 M  = { zw * w.x, zw * w.y };
    float2 u1 = { (z.x - M.x) * ir1, (z.y - M.y) * ir1 };

    { ushort2 wb = { f2bf(w.x),  f2bf(w.y)  }; *(ushort2*)&Bm[0][2 * t] = wb; }
    { ushort2 ub = { f2bf(u1.x), f2bf(u1.y) }; *(ushort2*)&Bm[1][2 * t] = ub; }

    // expansion labels (independent of everything below)
    if (t < NEXP) out[AUGT_OFF + BB + (size_t)j * NEXP + t] = (float)cls;
    __syncthreads();   // barrier A: Bm fully staged

    // ---- 2-wave MFMA Gram: wave w covers K-slice [w*256, w*256+256).
    if (wave < 2) {
        int row = lane & 31; if (row > 17) row = 17;
        int koff = (lane >> 5) * 8;
        const int kw = wave * 256;
        f32x16 acc = {0,0,0,0,0,0,0,0,0,0,0,0,0,0,0,0};
        #pragma unroll
        for (int stp = 0; stp < 16; ++stp) {
            bf16x8 av = *(const bf16x8*)&Bm[row][kw + stp * 16 + koff];
            acc = __builtin_amdgcn_mfma_f32_32x32x16_bf16(av, av, acc, 0, 0, 0);
        }
        // D layout: col = lane&31, row = (reg&3) + 8*(reg>>2) + 4*(lane>>5)
        int col = lane & 31;
        if (col < 18) {
            #pragma unroll
            for (int rg = 0; rg < 16; ++rg) {
                int rr = (rg & 3) + 8 * (rg >> 2) + 4 * (lane >> 5);
                if (rr < 18) pool.Gp[wave][rr][col] = acc[rg];
            }
        }
    }
    __syncthreads();   // barrier B: Gp complete

    // ---- wave 0: register-sum + register right-looking Cholesky, back-solve.
    if (wave == 0) {
        const int jl = (lane < 18) ? lane : 17;
        float Greg[18];
        #pragma unroll
        for (int c = 0; c < 18; ++c)
            Greg[c] = pool.Gp[0][jl][c] + pool.Gp[1][jl][c];

        float Lrow[18], idr[18];
        #pragma unroll
        for (int col = 0; col < 18; ++col) {
            float pivot = __shfl(Greg[col], col);
            float rsq = rsqrtf(pivot);
            idr[col] = rsq;
            float lv = (jl >= col) ? Greg[col] * rsq : 0.0f;
            Lrow[col] = lv;
            #pragma unroll
            for (int c = col + 1; c < 18; ++c) {
                float lc = __shfl(lv, c);
                Greg[c] -= lv * lc;
            }
        }
        #pragma unroll
        for (int c = 0; c < 18; ++c) pool.s.Ls[jl][c] = Lrow[c];

        if (lane < 16) {
            float b[18];
            b[0] = 0.0f;
            #pragma unroll
            for (int m = 1; m < 18; ++m) b[m] = bwg[17 + lane * 17 + (m - 1)];
            #pragma unroll
            for (int k = 17; k >= 0; --k) {
                float xk = b[k] * idr[k];
                pool.s.Cs[lane][k] = xk;
                #pragma unroll
                for (int m = 0; m < k; ++m)
                    b[m] -= pool.s.Ls[k][m] * xk;
            }
        }
    }
    __syncthreads();   // barrier C: Cs ready

    // ---- outputs: out_r = M + r1n * sum_j C[r][j] * b_j.
    float bx[18], by[18];
    #pragma unroll
    for (int jj = 0; jj < 18; ++jj) {
        uint v = *(const uint*)&Bm[jj][2 * t];
        bx[jj] = bf2f((ushort)(v & 0xffffu));
        by[jj] = bf2f((ushort)(v >> 16));
    }

    float* orow = out + ((size_t)BB + (size_t)j * NEXP) * DD;
    #pragma unroll
    for (int half = 0; half < 2; ++half) {
        float acc0[8], acc1[8];
        #pragma unroll
        for (int r = 0; r < 8; ++r) { acc0[r] = 0.0f; acc1[r] = 0.0f; }
        #pragma unroll
        for (int jj = 0; jj < 18; ++jj) {
            #pragma unroll
            for (int r = 0; r < 8; ++r) {
                float cc = pool.s.Cs[half * 8 + r][jj];
                acc0[r] += cc * bx[jj];
                acc1[r] += cc * by[jj];
            }
        }
        #pragma unroll
        for (int r = 0; r < 8; ++r) {
            float2 ov = { M.x + r1n * acc0[r], M.y + r1n * acc1[r] };
            ((float2*)(orow + (size_t)(half * 8 + r) * DD))[t] = ov;
        }
    }
}

// ---------------------------------------------------------------------------
extern "C" void kernel_launch(void* const* d_in, const int* in_sizes, int n_in,
                              void* d_out, int out_size, void* d_ws, size_t ws_size,
                              hipStream_t stream)
{
    const float* x     = (const float*)d_in[0];   // [8192,512]
    const int*   y     = (const int*)d_in[1];     // [8192]
    const float* prox  = (const float*)d_in[2];   // [11318,512]
    const float* bw    = (const float*)d_in[3];   // [17,17]
    const float* rands = (const float*)d_in[4];   // [2048,16,512]
    float* out = (float*)d_out;

    char* wsb = (char*)d_ws;
    double* scores = (double*)wsb;                            // 64 KB
    int* ranks = (int*)(wsb + 65536);                         // 32 KB
    int* sel   = (int*)(wsb + 65536 + 32768);                 // 8 KB
    float4* hdr = (float4*)(wsb + 114688);                    // 128 KB

    score_kernel<<<BB / 4, 256, 0, stream>>>(x, y, prox, scores, hdr, ranks);
    dim3 rgrid(BB / 256, BB / JCHUNK);
    rank_kernel<<<rgrid, 256, 0, stream>>>(scores, ranks);
    compact_kernel<<<1, 256, 0, stream>>>(ranks, sel, out);
    expand_kernel<<<TOPK + COPY_BLOCKS, 256, 0, stream>>>(x, y, prox, bw, rands,
                                                          sel, hdr, out);
}